// Round 8
// baseline (1671.215 us; speedup 1.0000x reference)
//
#include <hip/hip_runtime.h>
#include <hip/hip_bf16.h>
#include <math.h>

#define MIN_POINTS 4

// ---- workspace layout (bytes) ----
#define WS_W0P   0         // 192 f32 SoA: [0..63]=wx, [64..127]=wy, [128..191]=wz
#define WS_B0P   768       // 64 f32
#define WS_W1P   1024      // 4096 f32 folded, row-major [co][k]
#define WS_B1P   17408     // 64 f32
#define WS_CNT   17920     // V ints (400000 B)
#define WS_P0    417920    // partial0 [1024][16] f64 (131072 B)
#define WS_P1    548992    // part1 [1024][128] f64 (1048576 B)
#define NPART    1024
#define TS       68        // stats1 LDS tile row stride (floats)

// ---------------- K1: global stats of x (3-dim) + vertex counts ----------------
__global__ void k_stats0(const float4* __restrict__ d4, const int* __restrict__ idx,
                         double* __restrict__ partial0, int* __restrict__ cnt, int N){
  __shared__ double red[4][16];
  int tid = blockIdx.x*blockDim.x + threadIdx.x;
  int stride = gridDim.x*blockDim.x;
  double a[9] = {0,0,0,0,0,0,0,0,0};
  for (int i = tid; i < N; i += stride){
    float4 d = d4[i];
    double x0 = d.x, x1 = d.y, x2 = d.z;
    a[0] += x0; a[1] += x1; a[2] += x2;
    a[3] = fma(x0,x0,a[3]); a[4] = fma(x0,x1,a[4]); a[5] = fma(x0,x2,a[5]);
    a[6] = fma(x1,x1,a[6]); a[7] = fma(x1,x2,a[7]); a[8] = fma(x2,x2,a[8]);
    int v = idx[i]; if (v < 0) v = 0;
    atomicAdd(&cnt[v], 1);
  }
  int lane = threadIdx.x & 63, wid = threadIdx.x >> 6;
  #pragma unroll
  for (int j = 0; j < 9; j++){
    double v = a[j];
    for (int o = 32; o > 0; o >>= 1) v += __shfl_down(v, o, 64);
    if (lane == 0) red[wid][j] = v;
  }
  __syncthreads();
  if (threadIdx.x < 9){
    double s = red[0][threadIdx.x] + red[1][threadIdx.x]
             + red[2][threadIdx.x] + red[3][threadIdx.x];
    partial0[blockIdx.x*16 + threadIdx.x] = s;
  }
}

// ---------------- K2: reduce partials + fold layer-0 GN into W0' (SoA), b0' ----------------
__global__ void k_fold0(const double* __restrict__ partial0, const float* __restrict__ W0,
                        const float* __restrict__ g0, const float* __restrict__ bt0,
                        float* __restrict__ w0p, float* __restrict__ b0p, int N, int nparts){
  __shared__ double sred[16];
  int t = threadIdx.x, lane = t & 63, g = t >> 6;   // 1024 threads = 16 waves
  if (g < 9){
    double s = 0.0;
    for (int b = lane; b < nparts; b += 64) s += partial0[b*16 + g];
    for (int o = 32; o > 0; o >>= 1) s += __shfl_down(s, o, 64);
    if (lane == 0) sred[g] = s;
  }
  __syncthreads();
  if (t < 64){
    int c = t;
    double sx0 = sred[0], sx1 = sred[1], sx2 = sred[2];
    double G00 = sred[3], G01 = sred[4], G02 = sred[5], G11 = sred[6], G12 = sred[7], G22 = sred[8];
    double s[2], q[2];
    int chans[2] = { c, c ^ 1 };
    #pragma unroll
    for (int u = 0; u < 2; u++){
      int ch = chans[u];
      double w0 = W0[ch*3+0], w1 = W0[ch*3+1], w2 = W0[ch*3+2];
      s[u] = w0*sx0 + w1*sx1 + w2*sx2;
      q[u] = w0*w0*G00 + w1*w1*G11 + w2*w2*G22 + 2.0*(w0*w1*G01 + w0*w2*G02 + w1*w2*G12);
    }
    double inv  = 1.0 / (2.0 * (double)N);
    double mean = (s[0] + s[1]) * inv;
    double var  = (q[0] + q[1]) * inv - mean*mean;
    double aa   = (1.0 / sqrt(var + 1e-5)) * (double)g0[c];
    b0p[c] = (float)((double)bt0[c] - mean * aa);
    w0p[c]       = (float)((double)W0[c*3+0] * aa);
    w0p[64 + c]  = (float)((double)W0[c*3+1] * aa);
    w0p[128 + c] = (float)((double)W0[c*3+2] * aa);
  }
}

// ---------------- K3: per-channel sum/sumsq of raw y1 = h0 @ W1^T ----------------
// (unchanged — not the current bottleneck)
__global__ __launch_bounds__(256, 4)
void k_stats1(const float4* __restrict__ d4,
              const float* __restrict__ w0p, const float* __restrict__ b0p,
              const float* __restrict__ W1, double* __restrict__ part1,
              int N, int ntiles){
  __shared__ float stage[64][TS];      // h0 [row][ch]
  __shared__ double red[4][128];
  int lane = threadIdx.x & 63;
  int wid  = __builtin_amdgcn_readfirstlane((int)(threadIdx.x >> 6));
  int cbase = wid * 16;
  float w1r[64];
  #pragma unroll
  for (int k = 0; k < 64; k += 4){
    float4 t = *(const float4*)&W1[lane*64 + k];
    w1r[k]=t.x; w1r[k+1]=t.y; w1r[k+2]=t.z; w1r[k+3]=t.w;
  }
  double s0 = 0.0, s1 = 0.0;
  for (int t = blockIdx.x; t < ntiles; t += gridDim.x){
    int rb = t * 64;
    int row = rb + lane;
    float4 d = (row < N) ? d4[row] : make_float4(0.f,0.f,0.f,0.f);
    #pragma unroll
    for (int g = 0; g < 4; g++){
      int c = cbase + g*4;
      float4 h;
      h.x = fmaxf(fmaf(w0p[128+c+0], d.z, fmaf(w0p[64+c+0], d.y, fmaf(w0p[c+0], d.x, b0p[c+0]))), 0.f);
      h.y = fmaxf(fmaf(w0p[128+c+1], d.z, fmaf(w0p[64+c+1], d.y, fmaf(w0p[c+1], d.x, b0p[c+1]))), 0.f);
      h.z = fmaxf(fmaf(w0p[128+c+2], d.z, fmaf(w0p[64+c+2], d.y, fmaf(w0p[c+2], d.x, b0p[c+2]))), 0.f);
      h.w = fmaxf(fmaf(w0p[128+c+3], d.z, fmaf(w0p[64+c+3], d.y, fmaf(w0p[c+3], d.x, b0p[c+3]))), 0.f);
      *(float4*)&stage[lane][c] = h;
    }
    __syncthreads();              // stage complete
    #pragma unroll 2
    for (int rr = 0; rr < 16; rr++){
      int r = cbase + rr;                       // wave-uniform
      float a0 = 0.f, a1 = 0.f, a2 = 0.f, a3 = 0.f;
      #pragma unroll
      for (int kb = 0; kb < 16; kb++){
        float4 h = *(const float4*)&stage[r][kb*4];   // broadcast
        a0 = fmaf(w1r[kb*4+0], h.x, a0);
        a1 = fmaf(w1r[kb*4+1], h.y, a1);
        a2 = fmaf(w1r[kb*4+2], h.z, a2);
        a3 = fmaf(w1r[kb*4+3], h.w, a3);
      }
      if (rb + r < N){                          // uniform branch
        double y = (double)((a0 + a1) + (a2 + a3));
        s0 += y;
        s1 = fma(y, y, s1);
      }
    }
    __syncthreads();              // reads done before next tile overwrites stage
  }
  red[wid][lane]      = s0;
  red[wid][64 + lane] = s1;
  __syncthreads();
  if (threadIdx.x < 128){
    int t = threadIdx.x;
    part1[blockIdx.x*128 + t] = red[0][t] + red[1][t] + red[2][t] + red[3][t];
  }
}

// ---------------- K4: reduce partials + fold layer-1 GN into W1', b1' ----------------
__global__ void k_fold1(const double* __restrict__ part1, const float* __restrict__ W1,
                        const float* __restrict__ g1, const float* __restrict__ bt1,
                        float* __restrict__ w1p, float* __restrict__ b1p, int N, int nparts){
  __shared__ double sst[128];
  int t = threadIdx.x;          // 1024 threads
  int s = t >> 3, j = t & 7;    // 128 slots x 8 reducers
  double acc = 0.0;
  for (int b = j; b < nparts; b += 8) acc += part1[b*128 + s];
  acc += __shfl_down(acc, 4, 8);
  acc += __shfl_down(acc, 2, 8);
  acc += __shfl_down(acc, 1, 8);
  if (j == 0) sst[s] = acc;
  __syncthreads();
  if (t < 64){
    int c = t, p = c ^ 1;
    double inv  = 1.0 / (2.0 * (double)N);
    double mean = (sst[c] + sst[p]) * inv;
    double Ey2  = (sst[64+c] + sst[64+p]) * inv;
    double var  = Ey2 - mean*mean;
    double a    = (1.0 / sqrt(var + 1e-5)) * (double)g1[c];
    b1p[c] = (float)((double)bt1[c] - mean * a);
    for (int k = 0; k < 64; k++)
      w1p[c*64 + k] = (float)((double)W1[c*64 + k] * a);
  }
}

// ---------------- K5: fused main pass, lane = row, weights via s_load ----------------
// LDS cut to [64][33] (8.4 KB) so launch_bounds(64,4) reaches 16 waves/CU.
// h1 staged through the buffer in two lane-private 32-col halves (no barriers);
// y2 + atomics done in two 32-channel chunks (4 barriers/tile).
// Per-channel accumulation order identical to R7 (bit-identical output).
__global__ __launch_bounds__(64, 4)
void k_main(const float4* __restrict__ d4, const int* __restrict__ idx,
            const float* __restrict__ w0p, const float* __restrict__ b0p,
            const float* __restrict__ w1p, const float* __restrict__ b1p,
            const float* __restrict__ W2,  const float* __restrict__ b2,
            unsigned long long* __restrict__ seg, int N, int ntiles){
  __shared__ float buf[64][33];     // 8448 B; banks (lane+c)%32 -> 2-way, free
  int lane = threadIdx.x;           // 0..63, lane = row within tile
  for (int t = blockIdx.x; t < ntiles; t += gridDim.x){
    int rb  = t * 64;
    int row = rb + lane;
    float4 d = (row < N) ? d4[row] : make_float4(0.f,0.f,0.f,0.f);
    int myv = 0;
    if (row < N){ int v = idx[row]; myv = (v < 0) ? 0 : v; }
    // layer0: h0[64] per lane; weights wave-uniform (s_load)
    float h0[64];
    #pragma unroll
    for (int c = 0; c < 64; c++){
      float t0 = fmaf(w0p[128+c], d.z, fmaf(w0p[64+c], d.y, fmaf(w0p[c], d.x, b0p[c])));
      h0[c] = fmaxf(t0, 0.f);
    }
    float h1[64];
    // layer1 first half: c in [0,32) -> buf row `lane` (lane-private, no barrier)
    for (int c = 0; c < 32; c++){
      const float* wr = &w1p[c*64];             // uniform -> s_load
      float a0 = b1p[c], a1 = 0.f, a2 = 0.f, a3 = 0.f;
      #pragma unroll
      for (int k = 0; k < 64; k += 4){
        a0 = fmaf(wr[k+0], h0[k+0], a0);
        a1 = fmaf(wr[k+1], h0[k+1], a1);
        a2 = fmaf(wr[k+2], h0[k+2], a2);
        a3 = fmaf(wr[k+3], h0[k+3], a3);
      }
      buf[lane][c] = fmaxf((a0 + a1) + (a2 + a3), 0.f);
    }
    #pragma unroll
    for (int k = 0; k < 32; k++) h1[k] = buf[lane][k];      // static reg indices
    // layer1 second half: c in [32,64)
    for (int c = 32; c < 64; c++){
      const float* wr = &w1p[c*64];             // uniform -> s_load
      float a0 = b1p[c], a1 = 0.f, a2 = 0.f, a3 = 0.f;
      #pragma unroll
      for (int k = 0; k < 64; k += 4){
        a0 = fmaf(wr[k+0], h0[k+0], a0);
        a1 = fmaf(wr[k+1], h0[k+1], a1);
        a2 = fmaf(wr[k+2], h0[k+2], a2);
        a3 = fmaf(wr[k+3], h0[k+3], a3);
      }
      buf[lane][c - 32] = fmaxf((a0 + a1) + (a2 + a3), 0.f);
    }
    #pragma unroll
    for (int k = 0; k < 32; k++) h1[32 + k] = buf[lane][k]; // h0 dead from here
    // layer2 + atomics in two 32-channel chunks
    #pragma unroll 1
    for (int ci = 0; ci < 2; ci++){
      int cb = ci * 32;
      for (int cc = 0; cc < 32; cc++){
        int c = cb + cc;                        // uniform
        const float* wr = &W2[c*64];            // uniform -> s_load
        float a0 = b2[c], a1 = 0.f, a2 = 0.f, a3 = 0.f;
        #pragma unroll
        for (int k = 0; k < 64; k += 4){
          a0 = fmaf(wr[k+0], h1[k+0], a0);
          a1 = fmaf(wr[k+1], h1[k+1], a1);
          a2 = fmaf(wr[k+2], h1[k+2], a2);
          a3 = fmaf(wr[k+3], h1[k+3], a3);
        }
        buf[lane][cc] = fmaxf((a0 + a1) + (a2 + a3), 0.f);
      }
      __syncthreads();                          // all 64 rows of this chunk written
      // transposed atomic phase: lanes 0-31 -> row rr, lanes 32-63 -> row rr+32
      int jj = lane & 31;
      for (int rr = 0; rr < 32; rr++){
        int vA = __builtin_amdgcn_readlane(myv, rr);
        int vB = __builtin_amdgcn_readlane(myv, rr + 32);
        int r  = (lane < 32) ? rr : rr + 32;
        int v  = (lane < 32) ? vA : vB;
        float y = buf[r][jj];                   // 2 lanes/bank: free
        if (rb + r < N){
          unsigned int bits = __float_as_uint(y) & 0x7fffffffu;   // -0 -> +0
          unsigned long long packed = ((unsigned long long)bits << 32)
              | (unsigned long long)(unsigned int)(~(unsigned int)(rb + r));
          atomicMax(&seg[(size_t)v*64 + cb + jj], packed);
        }
      }
      __syncthreads();                          // reads done before chunk1/next-tile writes
    }
  }
}

// ---------------- K6: in-place unpack to final output ----------------
__global__ void k_out(const float4* __restrict__ d4, const int* __restrict__ cnt,
                      float* __restrict__ out, int N, int V){
  int lane = threadIdx.x & 63;
  int w = (int)((blockIdx.x*blockDim.x + threadIdx.x) >> 6);   // one wave per vertex
  if (w >= V) return;
  const unsigned long long* seg = (const unsigned long long*)out;
  unsigned long long p = seg[(size_t)w*64 + lane];
  int c = cnt[w];
  unsigned int bits = (unsigned int)(p >> 32);
  unsigned int rowu = ~(unsigned int)p;
  unsigned int nm1 = (unsigned int)(N - 1);
  if (rowu > nm1) rowu = nm1;
  float val  = __uint_as_float(bits);
  float bary = d4[rowu].w;
  bool few = (c < MIN_POINTS);
  float o0 = few ? 0.f : val;
  float o1 = few ? 0.f : bary;
  out[(size_t)w*128 + lane]      = o0;
  out[(size_t)w*128 + 64 + lane] = o1;
}

extern "C" void kernel_launch(void* const* d_in, const int* in_sizes, int n_in,
                              void* d_out, int out_size, void* d_ws, size_t ws_size,
                              hipStream_t stream) {
  const float4* d4  = (const float4*)d_in[0];
  const int*    idx = (const int*)d_in[1];
  const float*  W0  = (const float*)d_in[3];
  const float*  W1  = (const float*)d_in[4];
  const float*  W2  = (const float*)d_in[5];
  const float*  b2  = (const float*)d_in[6];
  const float*  g0  = (const float*)d_in[7];
  const float*  bt0 = (const float*)d_in[8];
  const float*  g1  = (const float*)d_in[9];
  const float*  bt1 = (const float*)d_in[10];

  int N = in_sizes[0] / 4;
  int V = out_size / 128;
  int ntiles = (N + 63) / 64;

  char* ws = (char*)d_ws;
  float*  w0p = (float*)(ws + WS_W0P);
  float*  b0p = (float*)(ws + WS_B0P);
  float*  w1p = (float*)(ws + WS_W1P);
  float*  b1p = (float*)(ws + WS_B1P);
  int*    cnt = (int*)(ws + WS_CNT);
  double* p0  = (double*)(ws + WS_P0);
  double* p1  = (double*)(ws + WS_P1);

  hipMemsetAsync(cnt, 0, (size_t)V * sizeof(int), stream);
  hipMemsetAsync(d_out, 0, (size_t)out_size * sizeof(float), stream);

  k_stats0<<<NPART, 256, 0, stream>>>(d4, idx, p0, cnt, N);
  k_fold0 <<<1, 1024, 0, stream>>>(p0, W0, g0, bt0, w0p, b0p, N, NPART);
  k_stats1<<<NPART, 256, 0, stream>>>(d4, w0p, b0p, W1, p1, N, ntiles);
  k_fold1 <<<1, 1024, 0, stream>>>(p1, W1, g1, bt1, w1p, b1p, N, NPART);
  k_main  <<<4096, 64, 0, stream>>>(d4, idx, w0p, b0p, w1p, b1p, W2, b2,
                                    (unsigned long long*)d_out, N, ntiles);
  k_out   <<<(V + 3) / 4, 256, 0, stream>>>(d4, cnt, (float*)d_out, N, V);
}

// Round 9
// 1107.824 us; speedup vs baseline: 1.5086x; 1.5086x over previous
//
#include <hip/hip_runtime.h>
#include <hip/hip_bf16.h>
#include <math.h>

#define MIN_POINTS 4

// ---- workspace layout (bytes) ----
#define WS_W0P   0         // 192 f32 SoA: [0..63]=wx, [64..127]=wy, [128..191]=wz
#define WS_B0P   768       // 64 f32
#define WS_W1P   1024      // 4096 f32 folded, row-major [co][k]
#define WS_B1P   17408     // 64 f32
#define WS_CNT   17920     // V ints (400000 B)
#define WS_P0    417920    // partial0 [1024][16] f64 (131072 B)
#define WS_P1    548992    // part1 [1024][128] f64 (1048576 B)
#define NPART    1024
#define TS       68        // stats1 LDS tile row stride (floats)

// ---------------- K1: global stats of x (3-dim) + vertex counts ----------------
__global__ void k_stats0(const float4* __restrict__ d4, const int* __restrict__ idx,
                         double* __restrict__ partial0, int* __restrict__ cnt, int N){
  __shared__ double red[4][16];
  int tid = blockIdx.x*blockDim.x + threadIdx.x;
  int stride = gridDim.x*blockDim.x;
  double a[9] = {0,0,0,0,0,0,0,0,0};
  for (int i = tid; i < N; i += stride){
    float4 d = d4[i];
    double x0 = d.x, x1 = d.y, x2 = d.z;
    a[0] += x0; a[1] += x1; a[2] += x2;
    a[3] = fma(x0,x0,a[3]); a[4] = fma(x0,x1,a[4]); a[5] = fma(x0,x2,a[5]);
    a[6] = fma(x1,x1,a[6]); a[7] = fma(x1,x2,a[7]); a[8] = fma(x2,x2,a[8]);
    int v = idx[i]; if (v < 0) v = 0;
    atomicAdd(&cnt[v], 1);
  }
  int lane = threadIdx.x & 63, wid = threadIdx.x >> 6;
  #pragma unroll
  for (int j = 0; j < 9; j++){
    double v = a[j];
    for (int o = 32; o > 0; o >>= 1) v += __shfl_down(v, o, 64);
    if (lane == 0) red[wid][j] = v;
  }
  __syncthreads();
  if (threadIdx.x < 9){
    double s = red[0][threadIdx.x] + red[1][threadIdx.x]
             + red[2][threadIdx.x] + red[3][threadIdx.x];
    partial0[blockIdx.x*16 + threadIdx.x] = s;
  }
}

// ---------------- K2: reduce partials + fold layer-0 GN into W0' (SoA), b0' ----------------
__global__ void k_fold0(const double* __restrict__ partial0, const float* __restrict__ W0,
                        const float* __restrict__ g0, const float* __restrict__ bt0,
                        float* __restrict__ w0p, float* __restrict__ b0p, int N, int nparts){
  __shared__ double sred[16];
  int t = threadIdx.x, lane = t & 63, g = t >> 6;   // 1024 threads = 16 waves
  if (g < 9){
    double s = 0.0;
    for (int b = lane; b < nparts; b += 64) s += partial0[b*16 + g];
    for (int o = 32; o > 0; o >>= 1) s += __shfl_down(s, o, 64);
    if (lane == 0) sred[g] = s;
  }
  __syncthreads();
  if (t < 64){
    int c = t;
    double sx0 = sred[0], sx1 = sred[1], sx2 = sred[2];
    double G00 = sred[3], G01 = sred[4], G02 = sred[5], G11 = sred[6], G12 = sred[7], G22 = sred[8];
    double s[2], q[2];
    int chans[2] = { c, c ^ 1 };
    #pragma unroll
    for (int u = 0; u < 2; u++){
      int ch = chans[u];
      double w0 = W0[ch*3+0], w1 = W0[ch*3+1], w2 = W0[ch*3+2];
      s[u] = w0*sx0 + w1*sx1 + w2*sx2;
      q[u] = w0*w0*G00 + w1*w1*G11 + w2*w2*G22 + 2.0*(w0*w1*G01 + w0*w2*G02 + w1*w2*G12);
    }
    double inv  = 1.0 / (2.0 * (double)N);
    double mean = (s[0] + s[1]) * inv;
    double var  = (q[0] + q[1]) * inv - mean*mean;
    double aa   = (1.0 / sqrt(var + 1e-5)) * (double)g0[c];
    b0p[c] = (float)((double)bt0[c] - mean * aa);
    w0p[c]       = (float)((double)W0[c*3+0] * aa);
    w0p[64 + c]  = (float)((double)W0[c*3+1] * aa);
    w0p[128 + c] = (float)((double)W0[c*3+2] * aa);
  }
}

// ---------------- K3: per-channel sum/sumsq of raw y1 = h0 @ W1^T ----------------
// (unchanged — not the current bottleneck)
__global__ __launch_bounds__(256, 4)
void k_stats1(const float4* __restrict__ d4,
              const float* __restrict__ w0p, const float* __restrict__ b0p,
              const float* __restrict__ W1, double* __restrict__ part1,
              int N, int ntiles){
  __shared__ float stage[64][TS];      // h0 [row][ch]
  __shared__ double red[4][128];
  int lane = threadIdx.x & 63;
  int wid  = __builtin_amdgcn_readfirstlane((int)(threadIdx.x >> 6));
  int cbase = wid * 16;
  float w1r[64];
  #pragma unroll
  for (int k = 0; k < 64; k += 4){
    float4 t = *(const float4*)&W1[lane*64 + k];
    w1r[k]=t.x; w1r[k+1]=t.y; w1r[k+2]=t.z; w1r[k+3]=t.w;
  }
  double s0 = 0.0, s1 = 0.0;
  for (int t = blockIdx.x; t < ntiles; t += gridDim.x){
    int rb = t * 64;
    int row = rb + lane;
    float4 d = (row < N) ? d4[row] : make_float4(0.f,0.f,0.f,0.f);
    #pragma unroll
    for (int g = 0; g < 4; g++){
      int c = cbase + g*4;
      float4 h;
      h.x = fmaxf(fmaf(w0p[128+c+0], d.z, fmaf(w0p[64+c+0], d.y, fmaf(w0p[c+0], d.x, b0p[c+0]))), 0.f);
      h.y = fmaxf(fmaf(w0p[128+c+1], d.z, fmaf(w0p[64+c+1], d.y, fmaf(w0p[c+1], d.x, b0p[c+1]))), 0.f);
      h.z = fmaxf(fmaf(w0p[128+c+2], d.z, fmaf(w0p[64+c+2], d.y, fmaf(w0p[c+2], d.x, b0p[c+2]))), 0.f);
      h.w = fmaxf(fmaf(w0p[128+c+3], d.z, fmaf(w0p[64+c+3], d.y, fmaf(w0p[c+3], d.x, b0p[c+3]))), 0.f);
      *(float4*)&stage[lane][c] = h;
    }
    __syncthreads();              // stage complete
    #pragma unroll 2
    for (int rr = 0; rr < 16; rr++){
      int r = cbase + rr;                       // wave-uniform
      float a0 = 0.f, a1 = 0.f, a2 = 0.f, a3 = 0.f;
      #pragma unroll
      for (int kb = 0; kb < 16; kb++){
        float4 h = *(const float4*)&stage[r][kb*4];   // broadcast
        a0 = fmaf(w1r[kb*4+0], h.x, a0);
        a1 = fmaf(w1r[kb*4+1], h.y, a1);
        a2 = fmaf(w1r[kb*4+2], h.z, a2);
        a3 = fmaf(w1r[kb*4+3], h.w, a3);
      }
      if (rb + r < N){                          // uniform branch
        double y = (double)((a0 + a1) + (a2 + a3));
        s0 += y;
        s1 = fma(y, y, s1);
      }
    }
    __syncthreads();              // reads done before next tile overwrites stage
  }
  red[wid][lane]      = s0;
  red[wid][64 + lane] = s1;
  __syncthreads();
  if (threadIdx.x < 128){
    int t = threadIdx.x;
    part1[blockIdx.x*128 + t] = red[0][t] + red[1][t] + red[2][t] + red[3][t];
  }
}

// ---------------- K4: reduce partials + fold layer-1 GN into W1', b1' ----------------
__global__ void k_fold1(const double* __restrict__ part1, const float* __restrict__ W1,
                        const float* __restrict__ g1, const float* __restrict__ bt1,
                        float* __restrict__ w1p, float* __restrict__ b1p, int N, int nparts){
  __shared__ double sst[128];
  int t = threadIdx.x;          // 1024 threads
  int s = t >> 3, j = t & 7;    // 128 slots x 8 reducers
  double acc = 0.0;
  for (int b = j; b < nparts; b += 8) acc += part1[b*128 + s];
  acc += __shfl_down(acc, 4, 8);
  acc += __shfl_down(acc, 2, 8);
  acc += __shfl_down(acc, 1, 8);
  if (j == 0) sst[s] = acc;
  __syncthreads();
  if (t < 64){
    int c = t, p = c ^ 1;
    double inv  = 1.0 / (2.0 * (double)N);
    double mean = (sst[c] + sst[p]) * inv;
    double Ey2  = (sst[64+c] + sst[64+p]) * inv;
    double var  = Ey2 - mean*mean;
    double a    = (1.0 / sqrt(var + 1e-5)) * (double)g1[c];
    b1p[c] = (float)((double)bt1[c] - mean * a);
    for (int k = 0; k < 64; k++)
      w1p[c*64 + k] = (float)((double)W1[c*64 + k] * a);
  }
}

// ---------------- K5: fused main pass — 4 waves share one 64-row tile ----------------
// R7 per-wave structure (lane = row, scalar weights, one 64-array live at a time,
// VGPR ~105) kept intact; each wave covers 16 channels per layer. Shared [64][65]
// buffer (16.6 KB/block) now serves 4 waves -> up to 32 waves/CU.
// launch_bounds(256,3) -> cap 170: R3/R4/R8 proved caps <=128+eps spill this live set.
// Per-channel accumulation order identical to R7 (bit-identical output).
__global__ __launch_bounds__(256, 3)
void k_main(const float4* __restrict__ d4, const int* __restrict__ idx,
            const float* __restrict__ w0p, const float* __restrict__ b0p,
            const float* __restrict__ w1p, const float* __restrict__ b1p,
            const float* __restrict__ W2,  const float* __restrict__ b2,
            unsigned long long* __restrict__ seg, int N, int ntiles){
  __shared__ float buf[64][65];     // h1 then y2 (aliased); banks (lane+c)%32 -> conflict-free
  int lane = threadIdx.x & 63;      // lane = row within tile
  int wid  = __builtin_amdgcn_readfirstlane((int)(threadIdx.x >> 6));
  int cbase = wid * 16;             // this wave's channel quarter
  for (int t = blockIdx.x; t < ntiles; t += gridDim.x){
    int rb  = t * 64;
    int row = rb + lane;
    float4 d = (row < N) ? d4[row] : make_float4(0.f,0.f,0.f,0.f);
    int myv = 0;
    if (row < N){ int v = idx[row]; myv = (v < 0) ? 0 : v; }
    // layer0: h0[64] per lane (duplicated across the 4 waves; ~10% extra VALU)
    float h0[64];
    #pragma unroll
    for (int c = 0; c < 64; c++){
      float t0 = fmaf(w0p[128+c], d.z, fmaf(w0p[64+c], d.y, fmaf(w0p[c], d.x, b0p[c])));
      h0[c] = fmaxf(t0, 0.f);
    }
    // layer1: this wave's 16 channels; scalar straight to LDS (column partition, no race)
    for (int cc = 0; cc < 16; cc++){
      int c = cbase + cc;                       // uniform
      const float* wr = &w1p[c*64];             // uniform -> s_load
      float a0 = b1p[c], a1 = 0.f, a2 = 0.f, a3 = 0.f;
      #pragma unroll
      for (int k = 0; k < 64; k += 4){
        a0 = fmaf(wr[k+0], h0[k+0], a0);
        a1 = fmaf(wr[k+1], h0[k+1], a1);
        a2 = fmaf(wr[k+2], h0[k+2], a2);
        a3 = fmaf(wr[k+3], h0[k+3], a3);
      }
      buf[lane][c] = fmaxf((a0 + a1) + (a2 + a3), 0.f);
    }
    __syncthreads();                  // bar1: h1 complete (all 64 cols)
    // reload full h1 into the registers h0 just vacated
    float h1[64];
    #pragma unroll
    for (int k = 0; k < 64; k++) h1[k] = buf[lane][k];
    __syncthreads();                  // bar2: all h1 reads done before y2 overwrites
    // layer2: this wave's 16 channels -> y2 into the aliased buffer
    for (int cc = 0; cc < 16; cc++){
      int c = cbase + cc;                       // uniform
      const float* wr = &W2[c*64];              // uniform -> s_load
      float a0 = b2[c], a1 = 0.f, a2 = 0.f, a3 = 0.f;
      #pragma unroll
      for (int k = 0; k < 64; k += 4){
        a0 = fmaf(wr[k+0], h1[k+0], a0);
        a1 = fmaf(wr[k+1], h1[k+1], a1);
        a2 = fmaf(wr[k+2], h1[k+2], a2);
        a3 = fmaf(wr[k+3], h1[k+3], a3);
      }
      buf[lane][c] = fmaxf((a0 + a1) + (a2 + a3), 0.f);
    }
    __syncthreads();                  // bar3: y2 complete
    // atomic phase: wave w owns rows [16w,16w+16); lane = channel -> coalesced 512B
    {
      int rmax = min(64, N - rb);
      for (int rr = 0; rr < 16; rr++){
        int r = cbase + rr;                     // uniform
        if (r < rmax){
          float y = buf[r][lane];               // column read, consecutive banks
          int v = __builtin_amdgcn_readlane(myv, r);   // uniform vertex of row r
          unsigned int bits = __float_as_uint(y) & 0x7fffffffu;  // -0 -> +0
          unsigned long long packed = ((unsigned long long)bits << 32)
              | (unsigned long long)(unsigned int)(~(unsigned int)(rb + r));
          atomicMax(&seg[(size_t)v*64 + lane], packed);
        }
      }
    }
    __syncthreads();                  // bar4: atomic reads done before next tile writes
  }
}

// ---------------- K6: in-place unpack to final output ----------------
__global__ void k_out(const float4* __restrict__ d4, const int* __restrict__ cnt,
                      float* __restrict__ out, int N, int V){
  int lane = threadIdx.x & 63;
  int w = (int)((blockIdx.x*blockDim.x + threadIdx.x) >> 6);   // one wave per vertex
  if (w >= V) return;
  const unsigned long long* seg = (const unsigned long long*)out;
  unsigned long long p = seg[(size_t)w*64 + lane];
  int c = cnt[w];
  unsigned int bits = (unsigned int)(p >> 32);
  unsigned int rowu = ~(unsigned int)p;
  unsigned int nm1 = (unsigned int)(N - 1);
  if (rowu > nm1) rowu = nm1;
  float val  = __uint_as_float(bits);
  float bary = d4[rowu].w;
  bool few = (c < MIN_POINTS);
  float o0 = few ? 0.f : val;
  float o1 = few ? 0.f : bary;
  out[(size_t)w*128 + lane]      = o0;
  out[(size_t)w*128 + 64 + lane] = o1;
}

extern "C" void kernel_launch(void* const* d_in, const int* in_sizes, int n_in,
                              void* d_out, int out_size, void* d_ws, size_t ws_size,
                              hipStream_t stream) {
  const float4* d4  = (const float4*)d_in[0];
  const int*    idx = (const int*)d_in[1];
  const float*  W0  = (const float*)d_in[3];
  const float*  W1  = (const float*)d_in[4];
  const float*  W2  = (const float*)d_in[5];
  const float*  b2  = (const float*)d_in[6];
  const float*  g0  = (const float*)d_in[7];
  const float*  bt0 = (const float*)d_in[8];
  const float*  g1  = (const float*)d_in[9];
  const float*  bt1 = (const float*)d_in[10];

  int N = in_sizes[0] / 4;
  int V = out_size / 128;
  int ntiles = (N + 63) / 64;

  char* ws = (char*)d_ws;
  float*  w0p = (float*)(ws + WS_W0P);
  float*  b0p = (float*)(ws + WS_B0P);
  float*  w1p = (float*)(ws + WS_W1P);
  float*  b1p = (float*)(ws + WS_B1P);
  int*    cnt = (int*)(ws + WS_CNT);
  double* p0  = (double*)(ws + WS_P0);
  double* p1  = (double*)(ws + WS_P1);

  hipMemsetAsync(cnt, 0, (size_t)V * sizeof(int), stream);
  hipMemsetAsync(d_out, 0, (size_t)out_size * sizeof(float), stream);

  k_stats0<<<NPART, 256, 0, stream>>>(d4, idx, p0, cnt, N);
  k_fold0 <<<1, 1024, 0, stream>>>(p0, W0, g0, bt0, w0p, b0p, N, NPART);
  k_stats1<<<NPART, 256, 0, stream>>>(d4, w0p, b0p, W1, p1, N, ntiles);
  k_fold1 <<<1, 1024, 0, stream>>>(p1, W1, g1, bt1, w1p, b1p, N, NPART);
  k_main  <<<2048, 256, 0, stream>>>(d4, idx, w0p, b0p, w1p, b1p, W2, b2,
                                     (unsigned long long*)d_out, N, ntiles);
  k_out   <<<(V + 3) / 4, 256, 0, stream>>>(d4, cnt, (float*)d_out, N, V);
}

// Round 10
// 796.755 us; speedup vs baseline: 2.0975x; 1.3904x over previous
//
#include <hip/hip_runtime.h>
#include <hip/hip_bf16.h>
#include <math.h>

#define MIN_POINTS 4

// ---- workspace layout (bytes) ----
#define WS_W0P   0         // 192 f32 SoA: [0..63]=wx, [64..127]=wy, [128..191]=wz
#define WS_B0P   768       // 64 f32
#define WS_W1P   1024      // 4096 f32 folded, row-major [co][k]
#define WS_B1P   17408     // 64 f32
#define WS_CNT   17920     // V ints (400000 B)
#define WS_P0    417920    // partial0 [1024][16] f64 (131072 B)
#define WS_P1    548992    // part1 [1024][128] f64 (1048576 B)
#define NPART    1024
#define TS       68        // stats1 LDS tile row stride (floats)

// ---------------- K1: global stats of x (3-dim) + vertex counts ----------------
__global__ void k_stats0(const float4* __restrict__ d4, const int* __restrict__ idx,
                         double* __restrict__ partial0, int* __restrict__ cnt, int N){
  __shared__ double red[4][16];
  int tid = blockIdx.x*blockDim.x + threadIdx.x;
  int stride = gridDim.x*blockDim.x;
  double a[9] = {0,0,0,0,0,0,0,0,0};
  for (int i = tid; i < N; i += stride){
    float4 d = d4[i];
    double x0 = d.x, x1 = d.y, x2 = d.z;
    a[0] += x0; a[1] += x1; a[2] += x2;
    a[3] = fma(x0,x0,a[3]); a[4] = fma(x0,x1,a[4]); a[5] = fma(x0,x2,a[5]);
    a[6] = fma(x1,x1,a[6]); a[7] = fma(x1,x2,a[7]); a[8] = fma(x2,x2,a[8]);
    int v = idx[i]; if (v < 0) v = 0;
    atomicAdd(&cnt[v], 1);
  }
  int lane = threadIdx.x & 63, wid = threadIdx.x >> 6;
  #pragma unroll
  for (int j = 0; j < 9; j++){
    double v = a[j];
    for (int o = 32; o > 0; o >>= 1) v += __shfl_down(v, o, 64);
    if (lane == 0) red[wid][j] = v;
  }
  __syncthreads();
  if (threadIdx.x < 9){
    double s = red[0][threadIdx.x] + red[1][threadIdx.x]
             + red[2][threadIdx.x] + red[3][threadIdx.x];
    partial0[blockIdx.x*16 + threadIdx.x] = s;
  }
}

// ---------------- K2: reduce partials + fold layer-0 GN into W0' (SoA), b0' ----------------
__global__ void k_fold0(const double* __restrict__ partial0, const float* __restrict__ W0,
                        const float* __restrict__ g0, const float* __restrict__ bt0,
                        float* __restrict__ w0p, float* __restrict__ b0p, int N, int nparts){
  __shared__ double sred[16];
  int t = threadIdx.x, lane = t & 63, g = t >> 6;   // 1024 threads = 16 waves
  if (g < 9){
    double s = 0.0;
    for (int b = lane; b < nparts; b += 64) s += partial0[b*16 + g];
    for (int o = 32; o > 0; o >>= 1) s += __shfl_down(s, o, 64);
    if (lane == 0) sred[g] = s;
  }
  __syncthreads();
  if (t < 64){
    int c = t;
    double sx0 = sred[0], sx1 = sred[1], sx2 = sred[2];
    double G00 = sred[3], G01 = sred[4], G02 = sred[5], G11 = sred[6], G12 = sred[7], G22 = sred[8];
    double s[2], q[2];
    int chans[2] = { c, c ^ 1 };
    #pragma unroll
    for (int u = 0; u < 2; u++){
      int ch = chans[u];
      double w0 = W0[ch*3+0], w1 = W0[ch*3+1], w2 = W0[ch*3+2];
      s[u] = w0*sx0 + w1*sx1 + w2*sx2;
      q[u] = w0*w0*G00 + w1*w1*G11 + w2*w2*G22 + 2.0*(w0*w1*G01 + w0*w2*G02 + w1*w2*G12);
    }
    double inv  = 1.0 / (2.0 * (double)N);
    double mean = (s[0] + s[1]) * inv;
    double var  = (q[0] + q[1]) * inv - mean*mean;
    double aa   = (1.0 / sqrt(var + 1e-5)) * (double)g0[c];
    b0p[c] = (float)((double)bt0[c] - mean * aa);
    w0p[c]       = (float)((double)W0[c*3+0] * aa);
    w0p[64 + c]  = (float)((double)W0[c*3+1] * aa);
    w0p[128 + c] = (float)((double)W0[c*3+2] * aa);
  }
}

// ---------------- K3: per-channel sum/sumsq of raw y1 = h0 @ W1^T ----------------
// (unchanged — not the current bottleneck)
__global__ __launch_bounds__(256, 4)
void k_stats1(const float4* __restrict__ d4,
              const float* __restrict__ w0p, const float* __restrict__ b0p,
              const float* __restrict__ W1, double* __restrict__ part1,
              int N, int ntiles){
  __shared__ float stage[64][TS];      // h0 [row][ch]
  __shared__ double red[4][128];
  int lane = threadIdx.x & 63;
  int wid  = __builtin_amdgcn_readfirstlane((int)(threadIdx.x >> 6));
  int cbase = wid * 16;
  float w1r[64];
  #pragma unroll
  for (int k = 0; k < 64; k += 4){
    float4 t = *(const float4*)&W1[lane*64 + k];
    w1r[k]=t.x; w1r[k+1]=t.y; w1r[k+2]=t.z; w1r[k+3]=t.w;
  }
  double s0 = 0.0, s1 = 0.0;
  for (int t = blockIdx.x; t < ntiles; t += gridDim.x){
    int rb = t * 64;
    int row = rb + lane;
    float4 d = (row < N) ? d4[row] : make_float4(0.f,0.f,0.f,0.f);
    #pragma unroll
    for (int g = 0; g < 4; g++){
      int c = cbase + g*4;
      float4 h;
      h.x = fmaxf(fmaf(w0p[128+c+0], d.z, fmaf(w0p[64+c+0], d.y, fmaf(w0p[c+0], d.x, b0p[c+0]))), 0.f);
      h.y = fmaxf(fmaf(w0p[128+c+1], d.z, fmaf(w0p[64+c+1], d.y, fmaf(w0p[c+1], d.x, b0p[c+1]))), 0.f);
      h.z = fmaxf(fmaf(w0p[128+c+2], d.z, fmaf(w0p[64+c+2], d.y, fmaf(w0p[c+2], d.x, b0p[c+2]))), 0.f);
      h.w = fmaxf(fmaf(w0p[128+c+3], d.z, fmaf(w0p[64+c+3], d.y, fmaf(w0p[c+3], d.x, b0p[c+3]))), 0.f);
      *(float4*)&stage[lane][c] = h;
    }
    __syncthreads();              // stage complete
    #pragma unroll 2
    for (int rr = 0; rr < 16; rr++){
      int r = cbase + rr;                       // wave-uniform
      float a0 = 0.f, a1 = 0.f, a2 = 0.f, a3 = 0.f;
      #pragma unroll
      for (int kb = 0; kb < 16; kb++){
        float4 h = *(const float4*)&stage[r][kb*4];   // broadcast
        a0 = fmaf(w1r[kb*4+0], h.x, a0);
        a1 = fmaf(w1r[kb*4+1], h.y, a1);
        a2 = fmaf(w1r[kb*4+2], h.z, a2);
        a3 = fmaf(w1r[kb*4+3], h.w, a3);
      }
      if (rb + r < N){                          // uniform branch
        double y = (double)((a0 + a1) + (a2 + a3));
        s0 += y;
        s1 = fma(y, y, s1);
      }
    }
    __syncthreads();              // reads done before next tile overwrites stage
  }
  red[wid][lane]      = s0;
  red[wid][64 + lane] = s1;
  __syncthreads();
  if (threadIdx.x < 128){
    int t = threadIdx.x;
    part1[blockIdx.x*128 + t] = red[0][t] + red[1][t] + red[2][t] + red[3][t];
  }
}

// ---------------- K4: reduce partials + fold layer-1 GN into W1', b1' ----------------
__global__ void k_fold1(const double* __restrict__ part1, const float* __restrict__ W1,
                        const float* __restrict__ g1, const float* __restrict__ bt1,
                        float* __restrict__ w1p, float* __restrict__ b1p, int N, int nparts){
  __shared__ double sst[128];
  int t = threadIdx.x;          // 1024 threads
  int s = t >> 3, j = t & 7;    // 128 slots x 8 reducers
  double acc = 0.0;
  for (int b = j; b < nparts; b += 8) acc += part1[b*128 + s];
  acc += __shfl_down(acc, 4, 8);
  acc += __shfl_down(acc, 2, 8);
  acc += __shfl_down(acc, 1, 8);
  if (j == 0) sst[s] = acc;
  __syncthreads();
  if (t < 64){
    int c = t, p = c ^ 1;
    double inv  = 1.0 / (2.0 * (double)N);
    double mean = (sst[c] + sst[p]) * inv;
    double Ey2  = (sst[64+c] + sst[64+p]) * inv;
    double var  = Ey2 - mean*mean;
    double a    = (1.0 / sqrt(var + 1e-5)) * (double)g1[c];
    b1p[c] = (float)((double)bt1[c] - mean * a);
    for (int k = 0; k < 64; k++)
      w1p[c*64 + k] = (float)((double)W1[c*64 + k] * a);
  }
}

// ---------------- K5: fused main pass — 4 waves share one 64-row tile ----------------
// R9 structure, but __launch_bounds__(256,2) -> VGPR cap 256: the ONLY cap that has
// ever held the h0/h1 live set (R6: 128 used @cap256; R7: 108 @cap256; caps 128/170
// spilled wholesale in R3/R4/R5/R8/R9). Occupancy comes from actual usage (~110-130
// -> 3-4 waves/SIMD) + shared 16.6 KB LDS (9 blocks/CU, not binding).
// Per-channel accumulation order identical to R7/R9 (bit-identical output).
__global__ __launch_bounds__(256, 2)
void k_main(const float4* __restrict__ d4, const int* __restrict__ idx,
            const float* __restrict__ w0p, const float* __restrict__ b0p,
            const float* __restrict__ w1p, const float* __restrict__ b1p,
            const float* __restrict__ W2,  const float* __restrict__ b2,
            unsigned long long* __restrict__ seg, int N, int ntiles){
  __shared__ float buf[64][65];     // h1 then y2 (aliased); banks (lane+c)%32 -> conflict-free
  int lane = threadIdx.x & 63;      // lane = row within tile
  int wid  = __builtin_amdgcn_readfirstlane((int)(threadIdx.x >> 6));
  int cbase = wid * 16;             // this wave's channel quarter
  for (int t = blockIdx.x; t < ntiles; t += gridDim.x){
    int rb  = t * 64;
    int row = rb + lane;
    float4 d = (row < N) ? d4[row] : make_float4(0.f,0.f,0.f,0.f);
    int myv = 0;
    if (row < N){ int v = idx[row]; myv = (v < 0) ? 0 : v; }
    // layer0: h0[64] per lane (duplicated across the 4 waves; ~10% extra VALU)
    float h0[64];
    #pragma unroll
    for (int c = 0; c < 64; c++){
      float t0 = fmaf(w0p[128+c], d.z, fmaf(w0p[64+c], d.y, fmaf(w0p[c], d.x, b0p[c])));
      h0[c] = fmaxf(t0, 0.f);
    }
    // layer1: this wave's 16 channels; scalar straight to LDS (column partition, no race)
    for (int cc = 0; cc < 16; cc++){
      int c = cbase + cc;                       // uniform
      const float* wr = &w1p[c*64];             // uniform -> s_load
      float a0 = b1p[c], a1 = 0.f, a2 = 0.f, a3 = 0.f;
      #pragma unroll
      for (int k = 0; k < 64; k += 4){
        a0 = fmaf(wr[k+0], h0[k+0], a0);
        a1 = fmaf(wr[k+1], h0[k+1], a1);
        a2 = fmaf(wr[k+2], h0[k+2], a2);
        a3 = fmaf(wr[k+3], h0[k+3], a3);
      }
      buf[lane][c] = fmaxf((a0 + a1) + (a2 + a3), 0.f);
    }
    __syncthreads();                  // bar1: h1 complete (all 64 cols)
    // reload full h1 into the registers h0 just vacated
    float h1[64];
    #pragma unroll
    for (int k = 0; k < 64; k++) h1[k] = buf[lane][k];
    __syncthreads();                  // bar2: all h1 reads done before y2 overwrites
    // layer2: this wave's 16 channels -> y2 into the aliased buffer
    for (int cc = 0; cc < 16; cc++){
      int c = cbase + cc;                       // uniform
      const float* wr = &W2[c*64];              // uniform -> s_load
      float a0 = b2[c], a1 = 0.f, a2 = 0.f, a3 = 0.f;
      #pragma unroll
      for (int k = 0; k < 64; k += 4){
        a0 = fmaf(wr[k+0], h1[k+0], a0);
        a1 = fmaf(wr[k+1], h1[k+1], a1);
        a2 = fmaf(wr[k+2], h1[k+2], a2);
        a3 = fmaf(wr[k+3], h1[k+3], a3);
      }
      buf[lane][c] = fmaxf((a0 + a1) + (a2 + a3), 0.f);
    }
    __syncthreads();                  // bar3: y2 complete
    // atomic phase: wave w owns rows [16w,16w+16); lane = channel -> coalesced 512B
    {
      int rmax = min(64, N - rb);
      for (int rr = 0; rr < 16; rr++){
        int r = cbase + rr;                     // uniform
        if (r < rmax){
          float y = buf[r][lane];               // column read, consecutive banks
          int v = __builtin_amdgcn_readlane(myv, r);   // uniform vertex of row r
          unsigned int bits = __float_as_uint(y) & 0x7fffffffu;  // -0 -> +0
          unsigned long long packed = ((unsigned long long)bits << 32)
              | (unsigned long long)(unsigned int)(~(unsigned int)(rb + r));
          atomicMax(&seg[(size_t)v*64 + lane], packed);
        }
      }
    }
    __syncthreads();                  // bar4: atomic reads done before next tile writes
  }
}

// ---------------- K6: in-place unpack to final output ----------------
__global__ void k_out(const float4* __restrict__ d4, const int* __restrict__ cnt,
                      float* __restrict__ out, int N, int V){
  int lane = threadIdx.x & 63;
  int w = (int)((blockIdx.x*blockDim.x + threadIdx.x) >> 6);   // one wave per vertex
  if (w >= V) return;
  const unsigned long long* seg = (const unsigned long long*)out;
  unsigned long long p = seg[(size_t)w*64 + lane];
  int c = cnt[w];
  unsigned int bits = (unsigned int)(p >> 32);
  unsigned int rowu = ~(unsigned int)p;
  unsigned int nm1 = (unsigned int)(N - 1);
  if (rowu > nm1) rowu = nm1;
  float val  = __uint_as_float(bits);
  float bary = d4[rowu].w;
  bool few = (c < MIN_POINTS);
  float o0 = few ? 0.f : val;
  float o1 = few ? 0.f : bary;
  out[(size_t)w*128 + lane]      = o0;
  out[(size_t)w*128 + 64 + lane] = o1;
}

extern "C" void kernel_launch(void* const* d_in, const int* in_sizes, int n_in,
                              void* d_out, int out_size, void* d_ws, size_t ws_size,
                              hipStream_t stream) {
  const float4* d4  = (const float4*)d_in[0];
  const int*    idx = (const int*)d_in[1];
  const float*  W0  = (const float*)d_in[3];
  const float*  W1  = (const float*)d_in[4];
  const float*  W2  = (const float*)d_in[5];
  const float*  b2  = (const float*)d_in[6];
  const float*  g0  = (const float*)d_in[7];
  const float*  bt0 = (const float*)d_in[8];
  const float*  g1  = (const float*)d_in[9];
  const float*  bt1 = (const float*)d_in[10];

  int N = in_sizes[0] / 4;
  int V = out_size / 128;
  int ntiles = (N + 63) / 64;

  char* ws = (char*)d_ws;
  float*  w0p = (float*)(ws + WS_W0P);
  float*  b0p = (float*)(ws + WS_B0P);
  float*  w1p = (float*)(ws + WS_W1P);
  float*  b1p = (float*)(ws + WS_B1P);
  int*    cnt = (int*)(ws + WS_CNT);
  double* p0  = (double*)(ws + WS_P0);
  double* p1  = (double*)(ws + WS_P1);

  hipMemsetAsync(cnt, 0, (size_t)V * sizeof(int), stream);
  hipMemsetAsync(d_out, 0, (size_t)out_size * sizeof(float), stream);

  k_stats0<<<NPART, 256, 0, stream>>>(d4, idx, p0, cnt, N);
  k_fold0 <<<1, 1024, 0, stream>>>(p0, W0, g0, bt0, w0p, b0p, N, NPART);
  k_stats1<<<NPART, 256, 0, stream>>>(d4, w0p, b0p, W1, p1, N, ntiles);
  k_fold1 <<<1, 1024, 0, stream>>>(p1, W1, g1, bt1, w1p, b1p, N, NPART);
  k_main  <<<2048, 256, 0, stream>>>(d4, idx, w0p, b0p, w1p, b1p, W2, b2,
                                     (unsigned long long*)d_out, N, ntiles);
  k_out   <<<(V + 3) / 4, 256, 0, stream>>>(d4, cnt, (float*)d_out, N, V);
}